// Round 4
// baseline (16950.264 us; speedup 1.0000x reference)
//
#include <hip/hip_runtime.h>

// Problem constants (from reference)
#define NN   4096         // interface size
#define HOR  1024         // horizon

// Per-step launch geometry: one wave per output row. 512 WGs x 512 thr.
#define NWG  512
#define TPB  512
#define WPW  8            // waves (rows) per workgroup

// ws layout (floats): [0, 2*NN) x ping-pong only (32 KB).
// x_{t+1} is written to buf[(t+1)&1]; step t>=1 reads buf[t&1].

__global__ void ddc_zero_out(float* __restrict__ out) {
    out[blockIdx.x * blockDim.x + threadIdx.x] = 0.f;   // <<<2,512>>> covers 1024
}

__global__ __launch_bounds__(TPB) void ddc_step_kernel(
    const int*   __restrict__ actions,
    const float* __restrict__ T_mats,
    const float* __restrict__ b_vecs,
    const float* __restrict__ R_vecs,
    float*       __restrict__ out,
    float*       __restrict__ xbuf,
    int t)
{
    const int wg   = blockIdx.x;
    const int tid  = threadIdx.x;
    const int wave = tid >> 6;
    const int lane = tid & 63;
    const int row  = wg * WPW + wave;

    __shared__ float xs[NN];          // 16 KB staged interface vector
    __shared__ float wred[WPW];

    const int a = actions[t];         // wave-uniform
    float val;

    if (t == 0) {
        // x0 = 0  ->  x1 = b[a0]; no matvec (x buffer holds poison at entry).
        val = b_vecs[a * NN + row];
    } else {
        // Stage x_t (16 KB) into LDS: 512 threads x 2 float4 (coalesced).
        const float4* xg = (const float4*)(xbuf + (t & 1) * NN);
        float4* xl = (float4*)xs;
        #pragma unroll
        for (int i = 0; i < (NN / 4) / TPB; ++i)
            xl[tid + i * TPB] = xg[tid + i * TPB];
        __syncthreads();

        // Row dot product; lane covers float4 idx = lane + 64k, k=0..15.
        // f64 accumulation: one f32 rounding per step instead of an
        // O(4096)-term f32 chain; ~0.8us/step VALU, hidden under memory.
        const float4* Trow =
            (const float4*)(T_mats + (((size_t)a) << 24) + (((size_t)row) << 12));
        const float4* xv4 = (const float4*)xs;
        double a0 = 0.0, a1 = 0.0, a2 = 0.0, a3 = 0.0;
        #pragma unroll
        for (int k = 0; k < 16; ++k) {
            const int idx = lane + (k << 6);
            float4 tv = Trow[idx];
            float4 xv = xv4[idx];
            a0 = fma((double)tv.x, (double)xv.x, a0);
            a1 = fma((double)tv.y, (double)xv.y, a1);
            a2 = fma((double)tv.z, (double)xv.z, a2);
            a3 = fma((double)tv.w, (double)xv.w, a3);
        }
        double acc = (a0 + a1) + (a2 + a3);
        #pragma unroll
        for (int off = 32; off > 0; off >>= 1)       // 64-lane butterfly
            acc += __shfl_xor(acc, off, 64);
        val = (float)(acc + (double)b_vecs[a * NN + row]);
    }

    if (lane == 0) {
        xbuf[((t + 1) & 1) * NN + row] = val;         // publish x_{t+1}[row]
        wred[wave] = val * R_vecs[a * NN + row];      // reward contribution
    }
    __syncthreads();
    if (tid == 0) {
        float s = 0.f;
        #pragma unroll
        for (int w = 0; w < WPW; ++w) s += wred[w];
        atomicAdd(&out[t], s);        // device-scope; one atomic per block
    }
}

extern "C" void kernel_launch(void* const* d_in, const int* in_sizes, int n_in,
                              void* d_out, int out_size, void* d_ws, size_t ws_size,
                              hipStream_t stream) {
    // Inputs (setup_inputs order): state[4096] (UNUSED), actions[1024] i32,
    // T_mats[4*4096*4096] f32, b_vecs[4*4096] f32, R_vecs[4*4096] f32.
    const int*   actions = (const int*)  d_in[1];
    const float* T_mats  = (const float*)d_in[2];
    const float* b_vecs  = (const float*)d_in[3];
    const float* R_vecs  = (const float*)d_in[4];
    float*       out     = (float*)d_out;
    float*       xbuf    = (float*)d_ws;      // 2*NN floats = 32 KB

    ddc_zero_out<<<dim3(2), dim3(TPB), 0, stream>>>(out);

    // One dispatch per recurrence step; stream order carries the dependency
    // (kernel-boundary release/acquire handles cross-XCD L2 visibility).
    for (int t = 0; t < HOR; ++t)
        ddc_step_kernel<<<dim3(NWG), dim3(TPB), 0, stream>>>(
            actions, T_mats, b_vecs, R_vecs, out, xbuf, t);
}

// Round 6
// 13502.141 us; speedup vs baseline: 1.2554x; 1.2554x over previous
//
#include <hip/hip_runtime.h>
#include <hip/hip_fp16.h>

// Problem constants (from reference)
#define NN   4096         // interface size
#define HOR  1024         // horizon

// Per-step launch geometry: one wave per output row. 512 WGs x 512 thr.
#define NWG  512
#define TPB  512
#define WPW  8            // waves (rows) per workgroup

// ws layout:
//   floats [0, 2*NN)       : x ping-pong (32 KB). x_{t+1} -> buf[(t+1)&1].
//   bytes  [32 KB, +128MB) : T converted to fp16 (4 * 4096 * 4096 halves)
// If ws_size is too small for the fp16 copy, fall back to the f32 path
// (round-4 kernel, known-good at 16.9 ms).

struct half4 { __half2 lo, hi; };

__global__ void ddc_zero_out(float* __restrict__ out) {
    out[blockIdx.x * blockDim.x + threadIdx.x] = 0.f;   // <<<2,512>>> covers 1024
}

// One-time (per launch) f32 -> fp16 conversion of all four T matrices.
__global__ __launch_bounds__(256) void ddc_convert_T(
    const float* __restrict__ src, __half2* __restrict__ dst, size_t n4)
{
    const float4* s4 = (const float4*)src;
    size_t i      = (size_t)blockIdx.x * blockDim.x + threadIdx.x;
    size_t stride = (size_t)gridDim.x * blockDim.x;
    for (size_t j = i; j < n4; j += stride) {
        float4 v = s4[j];
        dst[2 * j]     = __floats2half2_rn(v.x, v.y);
        dst[2 * j + 1] = __floats2half2_rn(v.z, v.w);
    }
}

// fp16-T step: T row is 8 KB; lane reads 8 B (half4) + 16 B of x per iter.
// x indexing identical to the known-good f32 kernel (conflict-free LDS).
__global__ __launch_bounds__(TPB) void ddc_step_fp16(
    const int*    __restrict__ actions,
    const __half* __restrict__ Th,
    const float*  __restrict__ b_vecs,
    const float*  __restrict__ R_vecs,
    float*        __restrict__ out,
    float*        __restrict__ xbuf,
    int t)
{
    const int wg   = blockIdx.x;
    const int tid  = threadIdx.x;
    const int wave = tid >> 6;
    const int lane = tid & 63;
    const int row  = wg * WPW + wave;

    __shared__ float xs[NN];
    __shared__ float wred[WPW];

    const int a = actions[t];
    float val;

    if (t == 0) {
        val = b_vecs[a * NN + row];
    } else {
        const float4* xg = (const float4*)(xbuf + (t & 1) * NN);
        float4* xl = (float4*)xs;
        #pragma unroll
        for (int i = 0; i < (NN / 4) / TPB; ++i)
            xl[tid + i * TPB] = xg[tid + i * TPB];
        __syncthreads();

        const half4* Trow =
            (const half4*)(Th + (((size_t)a) << 24) + (((size_t)row) << 12));
        const float4* xv4 = (const float4*)xs;
        double a0 = 0.0, a1 = 0.0, a2 = 0.0, a3 = 0.0;
        #pragma unroll
        for (int k = 0; k < 16; ++k) {
            const int idx = lane + (k << 6);
            half4  tv = Trow[idx];
            float4 xv = xv4[idx];
            float2 t01 = __half22float2(tv.lo);
            float2 t23 = __half22float2(tv.hi);
            a0 = fma((double)t01.x, (double)xv.x, a0);
            a1 = fma((double)t01.y, (double)xv.y, a1);
            a2 = fma((double)t23.x, (double)xv.z, a2);
            a3 = fma((double)t23.y, (double)xv.w, a3);
        }
        double acc = (a0 + a1) + (a2 + a3);
        #pragma unroll
        for (int off = 32; off > 0; off >>= 1)
            acc += __shfl_xor(acc, off, 64);
        val = (float)(acc + (double)b_vecs[a * NN + row]);
    }

    if (lane == 0) {
        xbuf[((t + 1) & 1) * NN + row] = val;
        wred[wave] = val * R_vecs[a * NN + row];
    }
    __syncthreads();
    if (tid == 0) {
        float s = 0.f;
        #pragma unroll
        for (int w = 0; w < WPW; ++w) s += wred[w];
        atomicAdd(&out[t], s);
    }
}

// f32 fallback (round-4 kernel, known-good).
__global__ __launch_bounds__(TPB) void ddc_step_f32(
    const int*   __restrict__ actions,
    const float* __restrict__ T_mats,
    const float* __restrict__ b_vecs,
    const float* __restrict__ R_vecs,
    float*       __restrict__ out,
    float*       __restrict__ xbuf,
    int t)
{
    const int wg   = blockIdx.x;
    const int tid  = threadIdx.x;
    const int wave = tid >> 6;
    const int lane = tid & 63;
    const int row  = wg * WPW + wave;

    __shared__ float xs[NN];
    __shared__ float wred[WPW];

    const int a = actions[t];
    float val;

    if (t == 0) {
        val = b_vecs[a * NN + row];
    } else {
        const float4* xg = (const float4*)(xbuf + (t & 1) * NN);
        float4* xl = (float4*)xs;
        #pragma unroll
        for (int i = 0; i < (NN / 4) / TPB; ++i)
            xl[tid + i * TPB] = xg[tid + i * TPB];
        __syncthreads();

        const float4* Trow =
            (const float4*)(T_mats + (((size_t)a) << 24) + (((size_t)row) << 12));
        const float4* xv4 = (const float4*)xs;
        double a0 = 0.0, a1 = 0.0, a2 = 0.0, a3 = 0.0;
        #pragma unroll
        for (int k = 0; k < 16; ++k) {
            const int idx = lane + (k << 6);
            float4 tv = Trow[idx];
            float4 xv = xv4[idx];
            a0 = fma((double)tv.x, (double)xv.x, a0);
            a1 = fma((double)tv.y, (double)xv.y, a1);
            a2 = fma((double)tv.z, (double)xv.z, a2);
            a3 = fma((double)tv.w, (double)xv.w, a3);
        }
        double acc = (a0 + a1) + (a2 + a3);
        #pragma unroll
        for (int off = 32; off > 0; off >>= 1)
            acc += __shfl_xor(acc, off, 64);
        val = (float)(acc + (double)b_vecs[a * NN + row]);
    }

    if (lane == 0) {
        xbuf[((t + 1) & 1) * NN + row] = val;
        wred[wave] = val * R_vecs[a * NN + row];
    }
    __syncthreads();
    if (tid == 0) {
        float s = 0.f;
        #pragma unroll
        for (int w = 0; w < WPW; ++w) s += wred[w];
        atomicAdd(&out[t], s);
    }
}

extern "C" void kernel_launch(void* const* d_in, const int* in_sizes, int n_in,
                              void* d_out, int out_size, void* d_ws, size_t ws_size,
                              hipStream_t stream) {
    // Inputs: state[4096] (UNUSED), actions[1024] i32, T_mats[4*4096*4096] f32,
    // b_vecs[4*4096] f32, R_vecs[4*4096] f32.
    const int*   actions = (const int*)  d_in[1];
    const float* T_mats  = (const float*)d_in[2];
    const float* b_vecs  = (const float*)d_in[3];
    const float* R_vecs  = (const float*)d_in[4];
    float*       out     = (float*)d_out;
    float*       xbuf    = (float*)d_ws;                    // 2*NN floats

    const size_t nT      = (size_t)4 * NN * NN;             // 67.1M elements
    const size_t need    = 2 * NN * sizeof(float) + nT * sizeof(__half);

    ddc_zero_out<<<dim3(2), dim3(TPB), 0, stream>>>(out);

    if (ws_size >= need) {
        __half* Th = (__half*)((char*)d_ws + 2 * NN * sizeof(float));
        ddc_convert_T<<<dim3(2048), dim3(256), 0, stream>>>(
            T_mats, (__half2*)Th, nT / 4);
        for (int t = 0; t < HOR; ++t)
            ddc_step_fp16<<<dim3(NWG), dim3(TPB), 0, stream>>>(
                actions, Th, b_vecs, R_vecs, out, xbuf, t);
    } else {
        for (int t = 0; t < HOR; ++t)
            ddc_step_f32<<<dim3(NWG), dim3(TPB), 0, stream>>>(
                actions, T_mats, b_vecs, R_vecs, out, xbuf, t);
    }
}